// Round 1
// baseline (1336.869 us; speedup 1.0000x reference)
//
#include <hip/hip_runtime.h>
#include <hip/hip_bf16.h>

#define ITER_TIME 32
#define DECAY 0.9f

typedef __attribute__((ext_vector_type(8))) short short8;
typedef __attribute__((ext_vector_type(4))) float f32x4;
typedef __attribute__((ext_vector_type(4))) short short4v;
typedef unsigned short ushort_t;
typedef unsigned int u32;

// global -> LDS direct DMA, 16B per lane. Dest is wave-uniform base + lane*16.
__device__ __forceinline__ void gload16(const ushort_t* g, ushort_t* l) {
    __builtin_amdgcn_global_load_lds(
        (const __attribute__((address_space(1))) u32*)g,
        (__attribute__((address_space(3))) u32*)l, 16, 0, 0);
}

// ---------------------------------------------------------------------------
// Convert f32 -> bf16 elementwise (for x)
// ---------------------------------------------------------------------------
__global__ void conv_f32_bf16(const float* __restrict__ in,
                              __hip_bfloat16* __restrict__ out, int n) {
    int i = blockIdx.x * 256 + threadIdx.x;
    if (i < n) out[i] = __float2bfloat16(in[i]);
}

// ---------------------------------------------------------------------------
// Fused convert + transpose: f32 in [R][C] -> bf16 out [C][R]
// ---------------------------------------------------------------------------
__global__ void transpose_f32_bf16(const float* __restrict__ in,
                                   __hip_bfloat16* __restrict__ out, int R,
                                   int C) {
    __shared__ float tile[32][33];
    int tx = threadIdx.x, ty = threadIdx.y;
    size_t x = blockIdx.x * 32 + tx;  // col in `in`
    size_t y = blockIdx.y * 32 + ty;  // row in `in`
    tile[ty][tx] = in[y * C + x];
    __syncthreads();
    size_t ox = blockIdx.y * 32 + tx;  // col in `out` (= row in `in`)
    size_t oy = blockIdx.x * 32 + ty;  // row in `out` (= col in `in`)
    out[oy * R + ox] = __float2bfloat16(tile[tx][ty]);
}

// ---------------------------------------------------------------------------
// Split-K GEMM v2: C_part[ks] = A[M=256 x K] * B (given as B^T rows [N][K]),
// bf16 inputs, f32 partials out.
// grid: (2, n_tiles, KS), block 256 (4 waves), tile 128x128, BK=64.
// Staging: global_load_lds width-16 into linear [128][64] LDS rows with an
// XOR swizzle applied on BOTH sides (inverse-swizzled per-lane global source,
// swizzled ds_read col). 2-phase double-buffer: STAGE(t+1) issued before
// compute(t); one __syncthreads per K-tile (its implicit vmcnt(0) drains the
// stage AFTER compute has hidden the latency).
// Tiles with by >= Nmain/128 take columns from BT2 (W_f) and write C2p.
// ---------------------------------------------------------------------------
__global__ __launch_bounds__(256)
void gemm_splitk(const ushort_t* __restrict__ A,    // [256][K] bf16
                 const ushort_t* __restrict__ BT,   // [Nmain][K] bf16
                 const ushort_t* __restrict__ BT2,  // [N2][K] bf16 (or null)
                 float* __restrict__ Cp,            // [KS][256][Nmain]
                 float* __restrict__ C2p,           // [KS][256][N2]
                 int K, int klen, int Nmain, int N2) {
    const int M = 256;
    __shared__ __attribute__((aligned(16))) ushort_t As[2][128 * 64];
    __shared__ __attribute__((aligned(16))) ushort_t Bs[2][128 * 64];

    int m0 = blockIdx.x * 128;
    int by = blockIdx.y;
    int ks = blockIdx.z;
    int ntile_main = Nmain >> 7;
    bool isB2 = (by >= ntile_main);
    const ushort_t* Bsrc = isB2 ? BT2 + (size_t)((by - ntile_main) * 128) * K
                                : BT + (size_t)(by * 128) * K;

    int t = threadIdx.x;
    int wave = t >> 6, lane = t & 63;
    int quad = lane >> 4, l16 = lane & 15;
    int wm = (wave >> 1) * 64, wn = (wave & 1) * 64;

    // --- staging addressing (global_load_lds) ---
    // Wave w stages chunks w*4..w*4+3 for A and B. Chunk c = 8 rows of 128B.
    // Lane l writes physical row r = c*8 + (l>>3), byte group (l&7)*16.
    // Swizzled content: logical col = ((l&7) ^ (l>>3)) * 8   (ushort units)
    int lr = lane >> 3;                  // row within chunk, == r&7
    int lcol = ((lane & 7) ^ lr) << 3;   // inverse-swizzled source col
    const ushort_t* aBase = A + (size_t)(m0 + wave * 32 + lr) * K + lcol;
    const ushort_t* bBase = Bsrc + (size_t)(wave * 32 + lr) * K + lcol;

    f32x4 acc[4][4];
#pragma unroll
    for (int i = 0; i < 4; i++)
#pragma unroll
        for (int j = 0; j < 4; j++) acc[i][j] = (f32x4){0.f, 0.f, 0.f, 0.f};

    int k0 = ks * klen;
    int nt = klen >> 6;

    // reader swizzle: physical col = ko ^ ((row&7)<<3); row&7 == l16&7
    int swz = (l16 & 7) << 3;

    auto stage = [&](int buf, int kk) {
#pragma unroll
        for (int i = 0; i < 4; ++i) {
            gload16(aBase + (size_t)(i * 8) * K + kk,
                    &As[buf][(wave * 4 + i) * 512]);
            gload16(bBase + (size_t)(i * 8) * K + kk,
                    &Bs[buf][(wave * 4 + i) * 512]);
        }
    };

    stage(0, k0);
    __syncthreads();  // implicit vmcnt(0): buf0 ready
    int cur = 0;
    for (int it = 0; it < nt; ++it) {
        if (it + 1 < nt) stage(cur ^ 1, k0 + (it + 1) * 64);  // in flight
#pragma unroll
        for (int kstep = 0; kstep < 2; ++kstep) {
            int ko = kstep * 32 + quad * 8;
            int pc = ko ^ swz;
            short8 af[4], bfr[4];
#pragma unroll
            for (int i = 0; i < 4; i++)
                af[i] = *(const short8*)&As[cur][(wm + i * 16 + l16) * 64 + pc];
#pragma unroll
            for (int j = 0; j < 4; j++)
                bfr[j] = *(const short8*)&Bs[cur][(wn + j * 16 + l16) * 64 + pc];
#pragma unroll
            for (int i = 0; i < 4; i++)
#pragma unroll
                for (int j = 0; j < 4; j++)
                    acc[i][j] = __builtin_amdgcn_mfma_f32_16x16x32_bf16(
                        af[i], bfr[j], acc[i][j], 0, 0, 0);
        }
        __syncthreads();  // drains next stage's vmcnt + publishes buf cur^1
        cur ^= 1;
    }

    // Epilogue: C/D layout col = lane&15, row = quad*4 + reg
#pragma unroll
    for (int i = 0; i < 4; i++) {
#pragma unroll
        for (int j = 0; j < 4; j++) {
            int gcol = by * 128 + wn + j * 16 + l16;
#pragma unroll
            for (int rr = 0; rr < 4; ++rr) {
                int grow = m0 + wm + i * 16 + quad * 4 + rr;
                float v = acc[i][j][rr];
                if (!isB2) {
                    Cp[(size_t)ks * M * Nmain + (size_t)grow * Nmain + gcol] = v;
                } else {
                    int c2 = gcol - Nmain;
                    C2p[(size_t)ks * M * N2 + (size_t)grow * N2 + c2] = v;
                }
            }
        }
    }
}

// ---------------------------------------------------------------------------
// Per-step elementwise (vectorized f32x4): reduce r partials, leaky-integrate,
// relu, emit act (f32) + a (bf16); also reduce f partials from the PREVIOUS
// step's GEMM into out[:,t-1,:]. At t==0 folds bias into i_ (writes back).
// ---------------------------------------------------------------------------
__global__ void elem_step(float* __restrict__ i_, float* __restrict__ u,
                          __hip_bfloat16* __restrict__ a,
                          const float* __restrict__ rp,
                          const float* __restrict__ fp,
                          const float* __restrict__ bias,
                          float* __restrict__ out, float* __restrict__ act,
                          int t, int KS) {
    int id4 = blockIdx.x * 256 + threadIdx.x;
    const int NU = 256 * 4096;
    const int NU4 = NU / 4;  // 262144
    if (id4 < NU4) {
        if (t >= ITER_TIME) return;  // final launch only reduces f
        int id = id4 * 4;
        int b = id >> 12, n = id & 4095;
        f32x4 un;
        if (t == 0) {
            f32x4 iv = *(f32x4*)&i_[id] + *(const f32x4*)&bias[n];
            *(f32x4*)&i_[id] = iv;  // subsequent steps read biased i_
            un = iv;                // u0 = 0, r0 = 0
        } else {
            f32x4 s = *(f32x4*)&i_[id];
            for (int k = 0; k < KS; ++k)
                s += *(const f32x4*)&rp[(size_t)k * NU + id];
            un = DECAY * *(f32x4*)&u[id] + s;
        }
        *(f32x4*)&u[id] = un;
        short4v av;
#pragma unroll
        for (int j = 0; j < 4; ++j) {
            float ar = un[j] > 0.f ? un[j] : 0.f;
            __hip_bfloat16 h = __float2bfloat16(ar);
            av[j] = *(short*)&h;
        }
        *(short4v*)&a[id] = av;
        *(f32x4*)&act[(size_t)b * (ITER_TIME * 4096) + (size_t)t * 4096 + n] =
            un;
    } else {
        if (t == 0) return;  // no f produced yet
        int id2 = (id4 - NU4) * 4;  // < 65536
        const int NF = 256 * 256;
        int b = id2 >> 8, d = id2 & 255;
        f32x4 fv = {0.f, 0.f, 0.f, 0.f};
        for (int k = 0; k < KS; ++k)
            fv += *(const f32x4*)&fp[(size_t)k * NF + id2];
        *(f32x4*)&out[(size_t)b * (ITER_TIME * 256) + (size_t)(t - 1) * 256 +
                      d] = fv;
    }
}

// ---------------------------------------------------------------------------
// Workspace layout (KS = 8, peak 0x4E80000 = 78.5 MiB; falls back to KS = 4,
// peak 0x3D80000 = 61.5 MiB, if ws_size is too small):
//   i_   0x0000000   4 MB  f32 [256][4096]
//   u    0x0400000   4 MB  f32 [256][4096]
//   a    0x0800000   2 MB  bf16 [256][4096]
//   rp   0x0A00000  KS*4 MB  f32 [KS][256][4096]  (WiT transiently lives here)
//   fp   rp+        KS*256 KB f32 [KS][256][256]
//   WrT  fp+        32 MB  bf16 [4096][4096]
//   WfT  WrT+        2 MB  bf16 [256][4096]
//   xb   WfT+      512 KB  bf16 [256][1024]
// ---------------------------------------------------------------------------
extern "C" void kernel_launch(void* const* d_in, const int* in_sizes, int n_in,
                              void* d_out, int out_size, void* d_ws,
                              size_t ws_size, hipStream_t stream) {
    const float* x = (const float*)d_in[0];    // [256][1024] f32
    const float* Wi = (const float*)d_in[1];   // [1024][4096] f32
    const float* bb = (const float*)d_in[2];   // [4096] f32
    const float* Wr = (const float*)d_in[3];   // [4096][4096] f32
    const float* Wf = (const float*)d_in[4];   // [4096][256] f32

    float* out = (float*)d_out;                        // [256][32][256]
    float* act = out + (size_t)256 * ITER_TIME * 256;  // [256][32][4096]

    int KS = 8;
    if (ws_size < (size_t)0x4E80000) KS = 4;  // fit guard

    char* ws = (char*)d_ws;
    float* i_ = (float*)(ws + 0x0);
    float* u = (float*)(ws + 0x400000);
    __hip_bfloat16* a = (__hip_bfloat16*)(ws + 0x800000);
    size_t off = 0xA00000;
    float* rp = (float*)(ws + off);
    off += (size_t)KS << 22;  // KS * 4 MB
    float* fp = (float*)(ws + off);
    off += (size_t)KS << 18;  // KS * 256 KB
    __hip_bfloat16* WrT = (__hip_bfloat16*)(ws + off);
    off += 0x2000000;
    __hip_bfloat16* WfT = (__hip_bfloat16*)(ws + off);
    off += 0x200000;
    __hip_bfloat16* xb = (__hip_bfloat16*)(ws + off);
    __hip_bfloat16* WiT = (__hip_bfloat16*)(ws + 0xA00000);  // transient in rp

    conv_f32_bf16<<<1024, 256, 0, stream>>>(x, xb, 256 * 1024);
    dim3 tb(32, 32);
    transpose_f32_bf16<<<dim3(128, 32), tb, 0, stream>>>(Wi, WiT, 1024, 4096);
    transpose_f32_bf16<<<dim3(128, 128), tb, 0, stream>>>(Wr, WrT, 4096, 4096);
    transpose_f32_bf16<<<dim3(8, 128), tb, 0, stream>>>(Wf, WfT, 4096, 256);

    // i_ = x @ W_i (no split-K; writes i_ directly as the single partial)
    gemm_splitk<<<dim3(2, 32, 1), 256, 0, stream>>>(
        (const ushort_t*)xb, (const ushort_t*)WiT, nullptr, i_, nullptr, 1024,
        1024, 4096, 256);

    int klen = 4096 / KS;
    for (int t = 0; t <= ITER_TIME; ++t) {
        elem_step<<<1088, 256, 0, stream>>>(i_, u, a, rp, fp, bb, out, act, t,
                                            KS);
        if (t < ITER_TIME) {
            // a @ [W_r | W_f]: N tiles 0..31 -> W_r, 32..33 -> W_f.
            gemm_splitk<<<dim3(2, 34, KS), 256, 0, stream>>>(
                (const ushort_t*)a, (const ushort_t*)WrT,
                (const ushort_t*)WfT, rp, fp, 4096, klen, 4096, 256);
        }
    }
}